// Round 10
// baseline (106.645 us; speedup 1.0000x reference)
//
#include <hip/hip_runtime.h>

// RenderMeshColor: B=16, P=100000, F=200000
// R10 = R9 split into two kernels to halve the per-phase L2 gather working set:
//   K_A: points-table gathers -> transform/proj/normals -> outputs 0,1,2,4
//   K_B: colors-table gathers -> output 3
// Both keep: XCD batch-grouping, dwordx3 gathers, LDS-staged nt-flush.

constexpr int Bn = 16;
constexpr int Pn = 100000;
constexpr int Fn = 200000;
constexpr int ChunksPerB = (Fn + 255) / 256;   // 782

constexpr size_t O0 = 0;
constexpr size_t O1 = (size_t)Bn * Fn * 9;
constexpr size_t O2 = O1 + (size_t)Bn * Fn * 6;
constexpr size_t O3 = O2 + (size_t)Bn * Fn * 1;
constexpr size_t O4 = O3 + (size_t)Bn * Fn * 9;

typedef float floatx4 __attribute__((ext_vector_type(4)));

// 12-byte vertex record — loads as one global_load_dwordx3.
struct V3 { float x, y, z; };

// BLAS-order 3-term dot: c = fma(a2,b2, fma(a1,b1, rn(a0*b0)))
__device__ __forceinline__ float dot3_blas(float a0, float a1, float a2,
                                           float b0, float b1, float b2) {
    return fmaf(a2, b2, fmaf(a1, b1, __fmul_rn(a0, b0)));
}

// Coalesced LDS->global flush with NONTEMPORAL stores (keeps the write stream
// from evicting gather tables out of the per-XCD L2 — verified R7->R9 -18us).
__device__ __forceinline__ void flush4(float* __restrict__ dst,
                                       const float* __restrict__ src,
                                       int nfloats, int tid) {
    const floatx4* s4 = (const floatx4*)src;
    floatx4* d4 = (floatx4*)dst;
    const int n4 = nfloats >> 2;
    for (int i = tid; i < n4; i += 256)
        __builtin_nontemporal_store(s4[i], &d4[i]);
}

// Shared decode of the XCD-grouped block id: XCD k serves batches {k, k+8}.
__device__ __forceinline__ void decode_block(int blid, int& b, int& blockStart) {
    const int xcd = blid & 7;
    const int s   = blid >> 3;
    b = xcd + 8 * (s / ChunksPerB);
    blockStart = (s % ChunksPerB) * 256;
}

// ---------------- K_A: points table only -> outputs 0,1,2,4 -----------------
__global__ __launch_bounds__(256, 8)
void points_kernel(const float* __restrict__ points,    // [B,P,3]
                   const int*   __restrict__ faces,     // [F,3]
                   const float* __restrict__ cam_rot,   // [B,3,3]
                   const float* __restrict__ cam_pos,   // [B,3]
                   const float* __restrict__ cam_proj,  // [3]
                   float* __restrict__ out)
{
    // LDS: (9+6+1+3)*256*4 = 19,456 B -> 8 blocks/CU.
    __shared__ __align__(16) float s3d[256 * 9];
    __shared__ __align__(16) float s2d[256 * 6];
    __shared__ __align__(16) float snz[256];
    __shared__ __align__(16) float sn1[256 * 3];

    int b, blockStart;
    decode_block(blockIdx.x, b, blockStart);

    const int t = threadIdx.x;
    const int f = blockStart + t;
    const int nvalid = min(256, Fn - blockStart);

    if (f < Fn) {
        const int i0 = faces[f * 3 + 0];
        const int i1 = faces[f * 3 + 1];
        const int i2 = faces[f * 3 + 2];

        const V3* pb = (const V3*)(points + (size_t)b * Pn * 3);
        const V3 p0 = pb[i0], p1 = pb[i1], p2 = pb[i2];

        const float r00 = cam_rot[b * 9 + 0], r01 = cam_rot[b * 9 + 1], r02 = cam_rot[b * 9 + 2];
        const float r10 = cam_rot[b * 9 + 3], r11 = cam_rot[b * 9 + 4], r12 = cam_rot[b * 9 + 5];
        const float r20 = cam_rot[b * 9 + 6], r21 = cam_rot[b * 9 + 7], r22 = cam_rot[b * 9 + 8];
        const float cp0 = cam_pos[b * 3 + 0], cp1 = cam_pos[b * 3 + 1], cp2 = cam_pos[b * 3 + 2];
        const float pj0 = cam_proj[0], pj1 = cam_proj[1], pj2 = cam_proj[2];

        const V3 pv[3] = {p0, p1, p2};
        float px[3][3];
#pragma unroll
        for (int v = 0; v < 3; ++v) {
            const float dx = __fsub_rn(pv[v].x, cp0);
            const float dy = __fsub_rn(pv[v].y, cp1);
            const float dz = __fsub_rn(pv[v].z, cp2);
            const float tx = dot3_blas(dx, dy, dz, r00, r01, r02);
            const float ty = dot3_blas(dx, dy, dz, r10, r11, r12);
            const float tz = dot3_blas(dx, dy, dz, r20, r21, r22);
            px[v][0] = tx; px[v][1] = ty; px[v][2] = tz;
            s3d[t * 9 + v * 3 + 0] = tx;
            s3d[t * 9 + v * 3 + 1] = ty;
            s3d[t * 9 + v * 3 + 2] = tz;
            const float zv = __fmul_rn(tz, pj2);
            s2d[t * 6 + v * 2 + 0] = __fdiv_rn(__fmul_rn(tx, pj0), zv);
            s2d[t * 6 + v * 2 + 1] = __fdiv_rn(__fmul_rn(ty, pj1), zv);
        }

        // normal = cross(p1-p0, p2-p0)
        const float e1x = px[1][0] - px[0][0], e1y = px[1][1] - px[0][1], e1z = px[1][2] - px[0][2];
        const float e2x = px[2][0] - px[0][0], e2y = px[2][1] - px[0][1], e2z = px[2][2] - px[0][2];
        const float nx = e1y * e2z - e1z * e2y;
        const float ny = e1z * e2x - e1x * e2z;
        const float nz = e1x * e2y - e1y * e2x;
        const float len = sqrtf(nx * nx + ny * ny + nz * nz);
        const float inv = 1.0f / (len + 1e-15f);

        snz[t] = nz;
        sn1[t * 3 + 0] = nx * inv;
        sn1[t * 3 + 1] = ny * inv;
        sn1[t * 3 + 2] = nz * inv;
    }

    __syncthreads();

    const size_t bf0 = (size_t)b * Fn + blockStart;
    flush4(out + O0 + bf0 * 9, s3d, nvalid * 9, t);
    flush4(out + O1 + bf0 * 6, s2d, nvalid * 6, t);
    flush4(out + O2 + bf0 * 1, snz, nvalid * 1, t);
    flush4(out + O4 + bf0 * 3, sn1, nvalid * 3, t);
}

// ---------------- K_B: colors table only -> output 3 ------------------------
__global__ __launch_bounds__(256, 8)
void colors_kernel(const float* __restrict__ tfcolor,   // [B,P,3]
                   const int*   __restrict__ faces,     // [F,3]
                   float* __restrict__ out)
{
    __shared__ __align__(16) float scl[256 * 9];   // 9,216 B -> occupancy-light

    int b, blockStart;
    decode_block(blockIdx.x, b, blockStart);

    const int t = threadIdx.x;
    const int f = blockStart + t;
    const int nvalid = min(256, Fn - blockStart);

    if (f < Fn) {
        const int i0 = faces[f * 3 + 0];
        const int i1 = faces[f * 3 + 1];
        const int i2 = faces[f * 3 + 2];

        const V3* cb = (const V3*)(tfcolor + (size_t)b * Pn * 3);
        const V3 c0v = cb[i0], c1v = cb[i1], c2v = cb[i2];

        scl[t * 9 + 0] = c0v.x; scl[t * 9 + 1] = c0v.y; scl[t * 9 + 2] = c0v.z;
        scl[t * 9 + 3] = c1v.x; scl[t * 9 + 4] = c1v.y; scl[t * 9 + 5] = c1v.z;
        scl[t * 9 + 6] = c2v.x; scl[t * 9 + 7] = c2v.y; scl[t * 9 + 8] = c2v.z;
    }

    __syncthreads();

    const size_t bf0 = (size_t)b * Fn + blockStart;
    flush4(out + O3 + bf0 * 9, scl, nvalid * 9, t);
}

extern "C" void kernel_launch(void* const* d_in, const int* in_sizes, int n_in,
                              void* d_out, int out_size, void* d_ws, size_t ws_size,
                              hipStream_t stream) {
    const float* points   = (const float*)d_in[0];
    const float* tfcolor  = (const float*)d_in[1];
    const int*   faces    = (const int*)d_in[2];
    const float* cam_rot  = (const float*)d_in[3];
    const float* cam_pos  = (const float*)d_in[4];
    const float* cam_proj = (const float*)d_in[5];
    float* out = (float*)d_out;

    dim3 block(256);
    dim3 grid(Bn * ChunksPerB);   // 12512 blocks each, XCD-swizzled in-kernel
    points_kernel<<<grid, block, 0, stream>>>(points, faces, cam_rot,
                                              cam_pos, cam_proj, out);
    colors_kernel<<<grid, block, 0, stream>>>(tfcolor, faces, out);
}